// Round 9
// baseline (485.950 us; speedup 1.0000x reference)
//
#include <hip/hip_runtime.h>

// GCN layer: out = relu( (1/max(deg,1)) * segsum_dst(order * (hW)[src]) + b )
// Round 9: round-8's k_gather kept VGPR=24 -- the `if(mine[u])` conditional
// gathers defeated load batching (serial predicated chains), and the
// half-split staged every payload twice. Fix: 1 block/bucket, branch-free
// 64-edge rounds (8 LDS reads -> 8 unconditional hw gathers -> 8 LDS
// atomics), masked tail loop. Only k_gather changed vs round 8.

constexpr int N_NODES = 100000;
constexpr int N_EDGES = 1600000;
constexpr int IN_F    = 64;
constexpr int OUT_F   = 32;
constexpr int SHIFT   = 6;                        // 64 nodes per bucket
constexpr int NPB     = 1 << SHIFT;               // 64
constexpr int NB      = (N_NODES + NPB - 1) >> SHIFT;   // 1563
constexpr int PCHUNK  = 3200;                     // edges per k_part block
constexpr int PBLOCKS = N_EDGES / PCHUNK;         // 500
constexpr int CBLOCKS = 128;
constexpr int CE      = N_EDGES / CBLOCKS;        // 12500
constexpr int CAP     = 1536;                     // payload LDS capacity (edges)

// ---------------- k1: hw = h @ W, fused zero of binTot ----------------
__global__ __launch_bounds__(256) void gemm64x32_zero(const float* __restrict__ h,
                                                      const float* __restrict__ W,
                                                      float* __restrict__ hw,
                                                      int* __restrict__ binTot) {
    __shared__ float Ws[IN_F * OUT_F];   // 8 KB
    __shared__ float hs[8 * IN_F];       // 2 KB
    const int tid = threadIdx.x;

    #pragma unroll
    for (int i = tid; i < IN_F * OUT_F; i += 256) Ws[i] = W[i];

    const int rowBase = blockIdx.x * 8;          // 12500 blocks
    ((float2*)hs)[tid] = ((const float2*)(h + (size_t)rowBase * IN_F))[tid];

    for (int i = blockIdx.x * 256 + tid; i < NB; i += gridDim.x * 256) binTot[i] = 0;

    __syncthreads();

    const int rl = tid >> 5;
    const int f  = tid & 31;
    float sum = 0.f;
    #pragma unroll
    for (int k = 0; k < IN_F; ++k)
        sum = fmaf(hs[rl * IN_F + k], Ws[k * OUT_F + f], sum);

    hw[(size_t)rowBase * OUT_F + tid] = sum;
}

// ---------------- k2: bucket histogram (LDS-aggregated) ----------------
__global__ __launch_bounds__(256) void k_count(const int* __restrict__ dst,
                                               int* __restrict__ binTot) {
    __shared__ int hist[NB];
    const int tid = threadIdx.x;
    for (int i = tid; i < NB; i += 256) hist[i] = 0;
    __syncthreads();
    const int base = blockIdx.x * CE;
    for (int j = tid; j < CE; j += 256)
        atomicAdd(&hist[dst[base + j] >> SHIFT], 1);
    __syncthreads();
    for (int c = tid; c < NB; c += 256) {
        const int v = hist[c];
        if (v) atomicAdd(&binTot[c], v);
    }
}

// ---------------- k3: exclusive scan of bucket totals (1 block, 256 thr) ----
__global__ __launch_bounds__(256) void k_scan(const int* __restrict__ binTot,
                                              int* __restrict__ binStart,
                                              int* __restrict__ cursor) {
    __shared__ int wt[4];
    const int tid = threadIdx.x, lane = tid & 63, wid = tid >> 6;
    const int base = tid * 8;
    int loc[8]; int run = 0;
    #pragma unroll
    for (int j = 0; j < 8; ++j) {
        const int i = base + j;
        const int c = (i < NB) ? binTot[i] : 0;
        loc[j] = run; run += c;
    }
    int s = run;
    #pragma unroll
    for (int d = 1; d < 64; d <<= 1) { const int t = __shfl_up(s, d); if (lane >= d) s += t; }
    if (lane == 63) wt[wid] = s;
    __syncthreads();
    int wex = 0;
    for (int w = 0; w < wid; ++w) wex += wt[w];
    const int tex = wex + s - run;
    #pragma unroll
    for (int j = 0; j < 8; ++j) {
        const int i = base + j;
        if (i < NB) { const int e = tex + loc[j]; binStart[i] = e; cursor[i] = e; }
    }
}

// ---------------- k4: partition edges into buckets (LDS sort, coalesced out) --
// payload: [ord f32 : 32][src : 17+][dstLow : 6]
__global__ __launch_bounds__(256, 2) void k_part(const int* __restrict__ src,
                                                 const int* __restrict__ dst,
                                                 const float* __restrict__ ord,
                                                 int* __restrict__ cursor,
                                                 unsigned long long* __restrict__ coarse) {
    __shared__ unsigned long long sorted[PCHUNK];   // 25.6 KB
    __shared__ unsigned short    binOf[PCHUNK];     //  6.4 KB
    __shared__ int hist[NB];                        //  6.25 KB
    __shared__ int rnk[NB];                         //  6.25 KB
    __shared__ int gbase[NB];                       //  6.25 KB
    __shared__ int sEx[NB];                         //  6.25 KB  (total ~57 KB)
    __shared__ int wt[4];
    const int tid = threadIdx.x, lane = tid & 63, wid = tid >> 6;
    const int ebase = blockIdx.x * PCHUNK;

    for (int i = tid; i < NB; i += 256) { hist[i] = 0; rnk[i] = 0; }
    __syncthreads();

    for (int j = tid; j < PCHUNK; j += 256)
        atomicAdd(&hist[dst[ebase + j] >> SHIFT], 1);
    __syncthreads();

    // hierarchical exclusive scan: hist -> sEx (8 bins/thread serial + wave shfl)
    {
        const int base = tid * 8;
        int loc[8]; int run = 0;
        #pragma unroll
        for (int j = 0; j < 8; ++j) {
            const int i = base + j;
            const int c = (i < NB) ? hist[i] : 0;
            loc[j] = run; run += c;
        }
        int s = run;
        #pragma unroll
        for (int d = 1; d < 64; d <<= 1) { const int t = __shfl_up(s, d); if (lane >= d) s += t; }
        if (lane == 63) wt[wid] = s;
        __syncthreads();
        int wex = 0;
        for (int w = 0; w < wid; ++w) wex += wt[w];
        const int tex = wex + s - run;
        #pragma unroll
        for (int j = 0; j < 8; ++j) {
            const int i = base + j;
            if (i < NB) sEx[i] = tex + loc[j];
        }
    }
    __syncthreads();

    // allocate this block's span in each bucket (exact CSR)
    for (int c = tid; c < NB; c += 256) {
        const int h = hist[c];
        if (h) gbase[c] = atomicAdd(&cursor[c], h);
    }

    // stage bucket-sorted payloads in LDS
    for (int j = tid; j < PCHUNK; j += 256) {
        const int e  = ebase + j;
        const int d_ = dst[e];
        const int c  = d_ >> SHIFT;
        const int r  = atomicAdd(&rnk[c], 1);
        const int slot = sEx[c] + r;
        sorted[slot] = ((unsigned long long)__float_as_uint(ord[e]) << 32) |
                       ((unsigned int)src[e] << SHIFT) | (unsigned int)(d_ & (NPB - 1));
        binOf[slot]  = (unsigned short)c;
    }
    __syncthreads();

    // coalesced copyout
    for (int i = tid; i < PCHUNK; i += 256) {
        const int c = binOf[i];
        coarse[(size_t)(gbase[c] + (i - sEx[c]))] = sorted[i];
    }
}

// ---------------- k5: per-bucket gather + LDS accumulate + finalize ----------
// 1 block per bucket. Payload chunk staged in LDS (coalesced). Hot loop is
// branch-free: 8 groups x unroll-8 -> 64 edges per round, 8 independent
// unconditional hw gathers per group (compiler can batch them).
__global__ __launch_bounds__(256, 4) void k_gather(const unsigned long long* __restrict__ coarse,
                                                   const int* __restrict__ binStart,
                                                   const int* __restrict__ binTot,
                                                   const float* __restrict__ hw,
                                                   const float* __restrict__ bias,
                                                   float* __restrict__ out) {
    __shared__ unsigned long long pay[CAP];   // 12.3 KB
    __shared__ float agg[NPB][OUT_F];         //  8 KB
    __shared__ float deg[NPB];                //  256 B
    const int tid = threadIdx.x;
    const int b   = blockIdx.x;
    const int g   = tid >> 5;     // 8 groups of 32 lanes
    const int f   = tid & 31;     // lane f -> LDS bank f

    for (int i = tid; i < NPB * OUT_F; i += 256) ((float*)agg)[i] = 0.f;
    if (tid < NPB) deg[tid] = 0.f;

    const int start = binStart[b];
    const int tot   = binTot[b];

    for (int base = 0; base < tot; base += CAP) {
        const int n = min(CAP, tot - base);
        __syncthreads();                          // pay reuse / agg-zero visibility
        for (int i = tid; i < n; i += 256)
            pay[i] = coarse[(size_t)start + base + i];
        __syncthreads();

        const int nfull = n & ~63;                // full 64-edge rounds

        // hot loop: branch-free, group g owns edges [jb+g*8, jb+g*8+8)
        for (int jb = 0; jb < nfull; jb += 64) {
            const int j0 = jb + g * 8;
            unsigned long long p[8];
            #pragma unroll
            for (int u = 0; u < 8; ++u) p[u] = pay[j0 + u];   // LDS broadcast

            float o[8]; int nd[8]; float v[8];
            #pragma unroll
            for (int u = 0; u < 8; ++u) {
                const unsigned sd = (unsigned)p[u];
                nd[u] = (int)(sd & (NPB - 1));
                o[u]  = __uint_as_float((unsigned)(p[u] >> 32));
                v[u]  = hw[(size_t)(sd >> SHIFT) * OUT_F + f];  // 8 independent loads
            }
            #pragma unroll
            for (int u = 0; u < 8; ++u) {
                atomicAdd(&agg[nd[u]][f], o[u] * v[u]);
                if (f == 0) atomicAdd(&deg[nd[u]], 1.0f);
            }
        }

        // masked tail (<64 edges): group-stride, 1 edge per group iteration
        for (int j = nfull + g; j < n; j += 8) {
            const unsigned long long p = pay[j];
            const unsigned sd = (unsigned)p;
            const float o = __uint_as_float((unsigned)(p >> 32));
            const float v = hw[(size_t)(sd >> SHIFT) * OUT_F + f];
            const int  nd = (int)(sd & (NPB - 1));
            atomicAdd(&agg[nd][f], o * v);
            if (f == 0) atomicAdd(&deg[nd], 1.0f);
        }
    }
    __syncthreads();

    // finalize: out = relu(agg * 1/max(deg,1) + b), coalesced store
    const int nodeBase = b * NPB;
    for (int i = tid; i < NPB * OUT_F; i += 256) {
        const int node = i >> 5;
        const int ff   = i & 31;
        const int gn   = nodeBase + node;
        if (gn < N_NODES) {
            const float norm = 1.0f / fmaxf(deg[node], 1.0f);
            out[(size_t)gn * OUT_F + ff] =
                fmaxf(fmaf(agg[node][ff], norm, bias[ff]), 0.f);
        }
    }
}

extern "C" void kernel_launch(void* const* d_in, const int* in_sizes, int n_in,
                              void* d_out, int out_size, void* d_ws, size_t ws_size,
                              hipStream_t stream) {
    const float* h   = (const float*)d_in[0];
    const int*   src = (const int*)  d_in[1];
    const int*   dst = (const int*)  d_in[2];
    const float* ord = (const float*)d_in[3];
    const float* W   = (const float*)d_in[4];
    const float* b   = (const float*)d_in[5];
    float*       out = (float*)d_out;

    // ws layout (~25.6 MB): coarse u64[E] | hw f32[N*32] | binTot | binStart | cursor
    unsigned long long* coarse = (unsigned long long*)d_ws;
    float* hw       = (float*)(coarse + N_EDGES);
    int*   binTot   = (int*)(hw + (size_t)N_NODES * OUT_F);
    int*   binStart = binTot + NB;
    int*   cursor   = binStart + NB;

    hipLaunchKernelGGL(gemm64x32_zero, dim3(N_NODES / 8), dim3(256), 0, stream,
                       h, W, hw, binTot);
    hipLaunchKernelGGL(k_count, dim3(CBLOCKS), dim3(256), 0, stream, dst, binTot);
    hipLaunchKernelGGL(k_scan, dim3(1), dim3(256), 0, stream,
                       binTot, binStart, cursor);
    hipLaunchKernelGGL(k_part, dim3(PBLOCKS), dim3(256), 0, stream,
                       src, dst, ord, cursor, coarse);
    hipLaunchKernelGGL(k_gather, dim3(NB), dim3(256), 0, stream,
                       coarse, binStart, binTot, hw, b, out);
}

// Round 12
// 228.952 us; speedup vs baseline: 2.1225x; 2.1225x over previous
//
#include <hip/hip_runtime.h>

// GCN layer: out = relu( (1/max(deg,1)) * segsum_dst(order * (hW)[src]) + b )
// Round 10 design (2nd resubmit; two consecutive GPU-acquisition timeouts):
// three ILP variants of the bucket/LDS-atomic gather all plateaued at ~310us
// -- the block structure itself is the wall. Round-4's flat 800K-thread
// register gather was <130us even with worse inputs. Plan: k_sort
// counting-sorts each bucket in LDS (in-place, coalesced writeback) and emits
// exact per-node CSR; k_gather2 is one thread per (node, f-quad), no
// LDS/atomics/syncs, fused finalize.

constexpr int N_NODES = 100000;
constexpr int N_EDGES = 1600000;
constexpr int IN_F    = 64;
constexpr int OUT_F   = 32;
constexpr int SHIFT   = 6;                        // 64 nodes per bucket
constexpr int NPB     = 1 << SHIFT;               // 64
constexpr int NB      = (N_NODES + NPB - 1) >> SHIFT;   // 1563
constexpr int PCHUNK  = 3200;                     // edges per k_part block
constexpr int PBLOCKS = N_EDGES / PCHUNK;         // 500
constexpr int CBLOCKS = 128;
constexpr int CE      = N_EDGES / CBLOCKS;        // 12500
constexpr int SCAP    = 2048;   // max edges per bucket; Binom mean 1024, max ~1170

// ---------------- k1: hw = h @ W, fused zero of binTot ----------------
__global__ __launch_bounds__(256) void gemm64x32_zero(const float* __restrict__ h,
                                                      const float* __restrict__ W,
                                                      float* __restrict__ hw,
                                                      int* __restrict__ binTot) {
    __shared__ float Ws[IN_F * OUT_F];   // 8 KB
    __shared__ float hs[8 * IN_F];       // 2 KB
    const int tid = threadIdx.x;

    #pragma unroll
    for (int i = tid; i < IN_F * OUT_F; i += 256) Ws[i] = W[i];

    const int rowBase = blockIdx.x * 8;          // 12500 blocks
    ((float2*)hs)[tid] = ((const float2*)(h + (size_t)rowBase * IN_F))[tid];

    for (int i = blockIdx.x * 256 + tid; i < NB; i += gridDim.x * 256) binTot[i] = 0;

    __syncthreads();

    const int rl = tid >> 5;
    const int f  = tid & 31;
    float sum = 0.f;
    #pragma unroll
    for (int k = 0; k < IN_F; ++k)
        sum = fmaf(hs[rl * IN_F + k], Ws[k * OUT_F + f], sum);

    hw[(size_t)rowBase * OUT_F + tid] = sum;
}

// ---------------- k2: bucket histogram (LDS-aggregated) ----------------
__global__ __launch_bounds__(256) void k_count(const int* __restrict__ dst,
                                               int* __restrict__ binTot) {
    __shared__ int hist[NB];
    const int tid = threadIdx.x;
    for (int i = tid; i < NB; i += 256) hist[i] = 0;
    __syncthreads();
    const int base = blockIdx.x * CE;
    for (int j = tid; j < CE; j += 256)
        atomicAdd(&hist[dst[base + j] >> SHIFT], 1);
    __syncthreads();
    for (int c = tid; c < NB; c += 256) {
        const int v = hist[c];
        if (v) atomicAdd(&binTot[c], v);
    }
}

// ---------------- k3: exclusive scan of bucket totals (1 block, 256 thr) ----
__global__ __launch_bounds__(256) void k_scan(const int* __restrict__ binTot,
                                              int* __restrict__ binStart,
                                              int* __restrict__ cursor) {
    __shared__ int wt[4];
    const int tid = threadIdx.x, lane = tid & 63, wid = tid >> 6;
    const int base = tid * 8;
    int loc[8]; int run = 0;
    #pragma unroll
    for (int j = 0; j < 8; ++j) {
        const int i = base + j;
        const int c = (i < NB) ? binTot[i] : 0;
        loc[j] = run; run += c;
    }
    int s = run;
    #pragma unroll
    for (int d = 1; d < 64; d <<= 1) { const int t = __shfl_up(s, d); if (lane >= d) s += t; }
    if (lane == 63) wt[wid] = s;
    __syncthreads();
    int wex = 0;
    for (int w = 0; w < wid; ++w) wex += wt[w];
    const int tex = wex + s - run;
    #pragma unroll
    for (int j = 0; j < 8; ++j) {
        const int i = base + j;
        if (i < NB) { const int e = tex + loc[j]; binStart[i] = e; cursor[i] = e; }
    }
}

// ---------------- k4: partition edges into buckets (LDS sort, coalesced out) --
// payload: [ord f32 : 32][src : 17+][dstLow : 6]
__global__ __launch_bounds__(256, 2) void k_part(const int* __restrict__ src,
                                                 const int* __restrict__ dst,
                                                 const float* __restrict__ ord,
                                                 int* __restrict__ cursor,
                                                 unsigned long long* __restrict__ coarse) {
    __shared__ unsigned long long sorted[PCHUNK];   // 25.6 KB
    __shared__ unsigned short    binOf[PCHUNK];     //  6.4 KB
    __shared__ int hist[NB];                        //  6.25 KB
    __shared__ int rnk[NB];                         //  6.25 KB
    __shared__ int gbase[NB];                       //  6.25 KB
    __shared__ int sEx[NB];                         //  6.25 KB  (total ~57 KB)
    __shared__ int wt[4];
    const int tid = threadIdx.x, lane = tid & 63, wid = tid >> 6;
    const int ebase = blockIdx.x * PCHUNK;

    for (int i = tid; i < NB; i += 256) { hist[i] = 0; rnk[i] = 0; }
    __syncthreads();

    for (int j = tid; j < PCHUNK; j += 256)
        atomicAdd(&hist[dst[ebase + j] >> SHIFT], 1);
    __syncthreads();

    // hierarchical exclusive scan: hist -> sEx (8 bins/thread serial + wave shfl)
    {
        const int base = tid * 8;
        int loc[8]; int run = 0;
        #pragma unroll
        for (int j = 0; j < 8; ++j) {
            const int i = base + j;
            const int c = (i < NB) ? hist[i] : 0;
            loc[j] = run; run += c;
        }
        int s = run;
        #pragma unroll
        for (int d = 1; d < 64; d <<= 1) { const int t = __shfl_up(s, d); if (lane >= d) s += t; }
        if (lane == 63) wt[wid] = s;
        __syncthreads();
        int wex = 0;
        for (int w = 0; w < wid; ++w) wex += wt[w];
        const int tex = wex + s - run;
        #pragma unroll
        for (int j = 0; j < 8; ++j) {
            const int i = base + j;
            if (i < NB) sEx[i] = tex + loc[j];
        }
    }
    __syncthreads();

    // allocate this block's span in each bucket (exact CSR)
    for (int c = tid; c < NB; c += 256) {
        const int h = hist[c];
        if (h) gbase[c] = atomicAdd(&cursor[c], h);
    }

    // stage bucket-sorted payloads in LDS
    for (int j = tid; j < PCHUNK; j += 256) {
        const int e  = ebase + j;
        const int d_ = dst[e];
        const int c  = d_ >> SHIFT;
        const int r  = atomicAdd(&rnk[c], 1);
        const int slot = sEx[c] + r;
        sorted[slot] = ((unsigned long long)__float_as_uint(ord[e]) << 32) |
                       ((unsigned int)src[e] << SHIFT) | (unsigned int)(d_ & (NPB - 1));
        binOf[slot]  = (unsigned short)c;
    }
    __syncthreads();

    // coalesced copyout
    for (int i = tid; i < PCHUNK; i += 256) {
        const int c = binOf[i];
        coarse[(size_t)(gbase[c] + (i - sEx[c]))] = sorted[i];
    }
}

// ---------------- k5: in-place counting sort of each bucket by node ----------
// Emits exact per-node CSR (nodeStart/nodeCnt). All global I/O coalesced.
__global__ __launch_bounds__(256, 4) void k_sort(unsigned long long* __restrict__ coarse,
                                                 const int* __restrict__ binStart,
                                                 const int* __restrict__ binTot,
                                                 int* __restrict__ nodeStart,
                                                 int* __restrict__ nodeCnt) {
    __shared__ unsigned long long pay[SCAP];    // 16 KB
    __shared__ unsigned long long pay2[SCAP];   // 16 KB
    __shared__ int cnt[NPB];
    __shared__ int cur[NPB];
    const int tid   = threadIdx.x;
    const int b     = blockIdx.x;
    const int start = binStart[b];
    const int tot   = binTot[b];

    if (tid < NPB) cnt[tid] = 0;
    __syncthreads();

    for (int i = tid; i < tot; i += 256) {
        const unsigned long long p = coarse[(size_t)start + i];
        pay[i] = p;
        atomicAdd(&cnt[(unsigned)p & (NPB - 1)], 1);
    }
    __syncthreads();

    // wave 0 scans the 64 counters and writes the node CSR
    if (tid < 64) {
        const int c = cnt[tid];
        int s = c;
        #pragma unroll
        for (int d = 1; d < 64; d <<= 1) { const int t = __shfl_up(s, d); if (tid >= d) s += t; }
        const int ex = s - c;
        cur[tid] = ex;
        nodeStart[b * NPB + tid] = start + ex;
        nodeCnt [b * NPB + tid] = c;
    }
    __syncthreads();

    // LDS scatter into sorted order
    for (int i = tid; i < tot; i += 256) {
        const unsigned long long p = pay[i];
        const int r = atomicAdd(&cur[(unsigned)p & (NPB - 1)], 1);
        pay2[r] = p;
    }
    __syncthreads();

    // coalesced in-place writeback
    for (int i = tid; i < tot; i += 256)
        coarse[(size_t)start + i] = pay2[i];
}

// ---------------- k6: flat per-node gather + fused finalize ----------------
// One thread per (node, f-quad): 800K threads, no LDS, no atomics, no syncs.
// Per edge: 8B payload (broadcast within the node's 8 threads) + float4 of hw.
__global__ __launch_bounds__(256, 8) void k_gather2(const unsigned long long* __restrict__ coarse,
                                                    const int* __restrict__ nodeStart,
                                                    const int* __restrict__ nodeCnt,
                                                    const float* __restrict__ hw,
                                                    const float* __restrict__ bias,
                                                    float* __restrict__ out) {
    const int i = blockIdx.x * 256 + threadIdx.x;   // 3125 * 256 = 800000 exact
    const int n = i >> 3;
    const int q = i & 7;

    const int st = nodeStart[n];
    const int dg = nodeCnt[n];

    float4 acc = make_float4(0.f, 0.f, 0.f, 0.f);
    for (int j = 0; j < dg; ++j) {
        const unsigned long long p = coarse[(size_t)st + j];
        const float o = __uint_as_float((unsigned)(p >> 32));
        const int   s = (int)(((unsigned)p) >> SHIFT);
        const float4 v = *(const float4*)(hw + (size_t)s * OUT_F + q * 4);
        acc.x = fmaf(o, v.x, acc.x);
        acc.y = fmaf(o, v.y, acc.y);
        acc.z = fmaf(o, v.z, acc.z);
        acc.w = fmaf(o, v.w, acc.w);
    }

    const float norm = 1.0f / fmaxf((float)dg, 1.0f);
    const float4 bb  = *(const float4*)(bias + q * 4);
    float4 r;
    r.x = fmaxf(fmaf(acc.x, norm, bb.x), 0.f);
    r.y = fmaxf(fmaf(acc.y, norm, bb.y), 0.f);
    r.z = fmaxf(fmaf(acc.z, norm, bb.z), 0.f);
    r.w = fmaxf(fmaf(acc.w, norm, bb.w), 0.f);
    *(float4*)(out + (size_t)n * OUT_F + q * 4) = r;
}

extern "C" void kernel_launch(void* const* d_in, const int* in_sizes, int n_in,
                              void* d_out, int out_size, void* d_ws, size_t ws_size,
                              hipStream_t stream) {
    const float* h   = (const float*)d_in[0];
    const int*   src = (const int*)  d_in[1];
    const int*   dst = (const int*)  d_in[2];
    const float* ord = (const float*)d_in[3];
    const float* W   = (const float*)d_in[4];
    const float* b   = (const float*)d_in[5];
    float*       out = (float*)d_out;

    // ws layout (~26.5 MB): coarse u64[E] | hw f32[N*32] |
    //   binTot[NB] | binStart[NB] | cursor[NB] | nodeStart[NB*64] | nodeCnt[NB*64]
    unsigned long long* coarse = (unsigned long long*)d_ws;
    float* hw        = (float*)(coarse + N_EDGES);
    int*   binTot    = (int*)(hw + (size_t)N_NODES * OUT_F);
    int*   binStart  = binTot + NB;
    int*   cursor    = binStart + NB;
    int*   nodeStart = cursor + NB;
    int*   nodeCnt   = nodeStart + NB * NPB;

    hipLaunchKernelGGL(gemm64x32_zero, dim3(N_NODES / 8), dim3(256), 0, stream,
                       h, W, hw, binTot);
    hipLaunchKernelGGL(k_count, dim3(CBLOCKS), dim3(256), 0, stream, dst, binTot);
    hipLaunchKernelGGL(k_scan, dim3(1), dim3(256), 0, stream,
                       binTot, binStart, cursor);
    hipLaunchKernelGGL(k_part, dim3(PBLOCKS), dim3(256), 0, stream,
                       src, dst, ord, cursor, coarse);
    hipLaunchKernelGGL(k_sort, dim3(NB), dim3(256), 0, stream,
                       coarse, binStart, binTot, nodeStart, nodeCnt);
    hipLaunchKernelGGL(k_gather2, dim3(N_NODES * 8 / 256), dim3(256), 0, stream,
                       coarse, nodeStart, nodeCnt, hw, b, out);
}

// Round 14
// 211.743 us; speedup vs baseline: 2.2950x; 1.0813x over previous
//
#include <hip/hip_runtime.h>

// GCN layer: out = relu( (1/max(deg,1)) * segsum_dst(order * (hW)[src]) + b )
// Round 13 design (resubmit; GPU-acquisition timeout): round-12 redesign
// landed (486 -> 229us). Top dispatch k_part (59us) at 15% occupancy -- 57KB
// LDS, 4 waves/block, barrier-phase latency. This round: more waves
// everywhere, pipeline unchanged.
//   k_part  256->512 thr (16 waves/CU), scan reworked for 512
//   k_sort  256->512 thr, (512,8) -> 4 blocks/CU = 32 waves
//   k_gather2: (256,8)=32-VGPR cap was serializing loads -> (256,6) + unroll-4
//   k_count 128->256 blocks

constexpr int N_NODES = 100000;
constexpr int N_EDGES = 1600000;
constexpr int IN_F    = 64;
constexpr int OUT_F   = 32;
constexpr int SHIFT   = 6;                        // 64 nodes per bucket
constexpr int NPB     = 1 << SHIFT;               // 64
constexpr int NB      = (N_NODES + NPB - 1) >> SHIFT;   // 1563
constexpr int PCHUNK  = 3200;                     // edges per k_part block
constexpr int PBLOCKS = N_EDGES / PCHUNK;         // 500
constexpr int PTH     = 512;                      // k_part threads
constexpr int CBLOCKS = 256;
constexpr int CE      = N_EDGES / CBLOCKS;        // 6250
constexpr int SCAP    = 2048;   // max edges per bucket; Binom mean 1024, max ~1170

// ---------------- k1: hw = h @ W, fused zero of binTot ----------------
__global__ __launch_bounds__(256) void gemm64x32_zero(const float* __restrict__ h,
                                                      const float* __restrict__ W,
                                                      float* __restrict__ hw,
                                                      int* __restrict__ binTot) {
    __shared__ float Ws[IN_F * OUT_F];   // 8 KB
    __shared__ float hs[8 * IN_F];       // 2 KB
    const int tid = threadIdx.x;

    #pragma unroll
    for (int i = tid; i < IN_F * OUT_F; i += 256) Ws[i] = W[i];

    const int rowBase = blockIdx.x * 8;          // 12500 blocks
    ((float2*)hs)[tid] = ((const float2*)(h + (size_t)rowBase * IN_F))[tid];

    for (int i = blockIdx.x * 256 + tid; i < NB; i += gridDim.x * 256) binTot[i] = 0;

    __syncthreads();

    const int rl = tid >> 5;
    const int f  = tid & 31;
    float sum = 0.f;
    #pragma unroll
    for (int k = 0; k < IN_F; ++k)
        sum = fmaf(hs[rl * IN_F + k], Ws[k * OUT_F + f], sum);

    hw[(size_t)rowBase * OUT_F + tid] = sum;
}

// ---------------- k2: bucket histogram (LDS-aggregated) ----------------
__global__ __launch_bounds__(256) void k_count(const int* __restrict__ dst,
                                               int* __restrict__ binTot) {
    __shared__ int hist[NB];
    const int tid = threadIdx.x;
    for (int i = tid; i < NB; i += 256) hist[i] = 0;
    __syncthreads();
    const int base = blockIdx.x * CE;
    for (int j = tid; j < CE; j += 256)
        atomicAdd(&hist[dst[base + j] >> SHIFT], 1);
    __syncthreads();
    for (int c = tid; c < NB; c += 256) {
        const int v = hist[c];
        if (v) atomicAdd(&binTot[c], v);
    }
}

// ---------------- k3: exclusive scan of bucket totals (1 block, 256 thr) ----
__global__ __launch_bounds__(256) void k_scan(const int* __restrict__ binTot,
                                              int* __restrict__ binStart,
                                              int* __restrict__ cursor) {
    __shared__ int wt[4];
    const int tid = threadIdx.x, lane = tid & 63, wid = tid >> 6;
    const int base = tid * 8;
    int loc[8]; int run = 0;
    #pragma unroll
    for (int j = 0; j < 8; ++j) {
        const int i = base + j;
        const int c = (i < NB) ? binTot[i] : 0;
        loc[j] = run; run += c;
    }
    int s = run;
    #pragma unroll
    for (int d = 1; d < 64; d <<= 1) { const int t = __shfl_up(s, d); if (lane >= d) s += t; }
    if (lane == 63) wt[wid] = s;
    __syncthreads();
    int wex = 0;
    for (int w = 0; w < wid; ++w) wex += wt[w];
    const int tex = wex + s - run;
    #pragma unroll
    for (int j = 0; j < 8; ++j) {
        const int i = base + j;
        if (i < NB) { const int e = tex + loc[j]; binStart[i] = e; cursor[i] = e; }
    }
}

// ---------------- k4: partition edges into buckets (LDS sort, coalesced out) --
// payload: [ord f32 : 32][src : 17+][dstLow : 6].  512 threads, 8 waves.
__global__ __launch_bounds__(PTH, 4) void k_part(const int* __restrict__ src,
                                                 const int* __restrict__ dst,
                                                 const float* __restrict__ ord,
                                                 int* __restrict__ cursor,
                                                 unsigned long long* __restrict__ coarse) {
    __shared__ unsigned long long sorted[PCHUNK];   // 25.6 KB
    __shared__ unsigned short    binOf[PCHUNK];     //  6.4 KB
    __shared__ int hist[NB];                        //  6.25 KB
    __shared__ int rnk[NB];                         //  6.25 KB
    __shared__ int gbase[NB];                       //  6.25 KB
    __shared__ int sEx[NB];                         //  6.25 KB  (total ~57 KB)
    __shared__ int wt[PTH / 64];
    const int tid = threadIdx.x, lane = tid & 63, wid = tid >> 6;
    const int ebase = blockIdx.x * PCHUNK;

    for (int i = tid; i < NB; i += PTH) { hist[i] = 0; rnk[i] = 0; }
    __syncthreads();

    for (int j = tid; j < PCHUNK; j += PTH)
        atomicAdd(&hist[dst[ebase + j] >> SHIFT], 1);
    __syncthreads();

    // hierarchical exclusive scan: hist -> sEx (4 bins/thread + 8-wave hierarchy)
    {
        const int base = tid * 4;                   // 512*4 = 2048 >= NB
        int loc[4]; int run = 0;
        #pragma unroll
        for (int j = 0; j < 4; ++j) {
            const int i = base + j;
            const int c = (i < NB) ? hist[i] : 0;
            loc[j] = run; run += c;
        }
        int s = run;
        #pragma unroll
        for (int d = 1; d < 64; d <<= 1) { const int t = __shfl_up(s, d); if (lane >= d) s += t; }
        if (lane == 63) wt[wid] = s;
        __syncthreads();
        int wex = 0;
        for (int w = 0; w < wid; ++w) wex += wt[w];
        const int tex = wex + s - run;
        #pragma unroll
        for (int j = 0; j < 4; ++j) {
            const int i = base + j;
            if (i < NB) sEx[i] = tex + loc[j];
        }
    }
    __syncthreads();

    // allocate this block's span in each bucket (exact CSR)
    for (int c = tid; c < NB; c += PTH) {
        const int h = hist[c];
        if (h) gbase[c] = atomicAdd(&cursor[c], h);
    }

    // stage bucket-sorted payloads in LDS
    for (int j = tid; j < PCHUNK; j += PTH) {
        const int e  = ebase + j;
        const int d_ = dst[e];
        const int c  = d_ >> SHIFT;
        const int r  = atomicAdd(&rnk[c], 1);
        const int slot = sEx[c] + r;
        sorted[slot] = ((unsigned long long)__float_as_uint(ord[e]) << 32) |
                       ((unsigned int)src[e] << SHIFT) | (unsigned int)(d_ & (NPB - 1));
        binOf[slot]  = (unsigned short)c;
    }
    __syncthreads();

    // coalesced copyout
    for (int i = tid; i < PCHUNK; i += PTH) {
        const int c = binOf[i];
        coarse[(size_t)(gbase[c] + (i - sEx[c]))] = sorted[i];
    }
}

// ---------------- k5: in-place counting sort of each bucket by node ----------
// Emits exact per-node CSR (nodeStart/nodeCnt). All global I/O coalesced.
__global__ __launch_bounds__(512, 8) void k_sort(unsigned long long* __restrict__ coarse,
                                                 const int* __restrict__ binStart,
                                                 const int* __restrict__ binTot,
                                                 int* __restrict__ nodeStart,
                                                 int* __restrict__ nodeCnt) {
    __shared__ unsigned long long pay[SCAP];    // 16 KB
    __shared__ unsigned long long pay2[SCAP];   // 16 KB
    __shared__ int cnt[NPB];
    __shared__ int cur[NPB];
    const int tid   = threadIdx.x;
    const int b     = blockIdx.x;
    const int start = binStart[b];
    const int tot   = binTot[b];

    if (tid < NPB) cnt[tid] = 0;
    __syncthreads();

    for (int i = tid; i < tot; i += 512) {
        const unsigned long long p = coarse[(size_t)start + i];
        pay[i] = p;
        atomicAdd(&cnt[(unsigned)p & (NPB - 1)], 1);
    }
    __syncthreads();

    // wave 0 scans the 64 counters and writes the node CSR
    if (tid < 64) {
        const int c = cnt[tid];
        int s = c;
        #pragma unroll
        for (int d = 1; d < 64; d <<= 1) { const int t = __shfl_up(s, d); if (tid >= d) s += t; }
        const int ex = s - c;
        cur[tid] = ex;
        nodeStart[b * NPB + tid] = start + ex;
        nodeCnt [b * NPB + tid] = c;
    }
    __syncthreads();

    // LDS scatter into sorted order
    for (int i = tid; i < tot; i += 512) {
        const unsigned long long p = pay[i];
        const int r = atomicAdd(&cur[(unsigned)p & (NPB - 1)], 1);
        pay2[r] = p;
    }
    __syncthreads();

    // coalesced in-place writeback
    for (int i = tid; i < tot; i += 512)
        coarse[(size_t)start + i] = pay2[i];
}

// ---------------- k6: flat per-node gather + fused finalize ----------------
// One thread per (node, f-quad): 800K threads, no LDS, no atomics, no syncs.
// Branch-free unroll-4 main loop (independent payload + hw loads) + tail.
__global__ __launch_bounds__(256, 6) void k_gather2(const unsigned long long* __restrict__ coarse,
                                                    const int* __restrict__ nodeStart,
                                                    const int* __restrict__ nodeCnt,
                                                    const float* __restrict__ hw,
                                                    const float* __restrict__ bias,
                                                    float* __restrict__ out) {
    const int i = blockIdx.x * 256 + threadIdx.x;   // 3125 * 256 = 800000 exact
    const int n = i >> 3;
    const int q = i & 7;

    const int st = nodeStart[n];
    const int dg = nodeCnt[n];

    float4 acc = make_float4(0.f, 0.f, 0.f, 0.f);
    const int full = dg & ~3;
    int j = 0;
    for (; j < full; j += 4) {
        const unsigned long long p0 = coarse[(size_t)st + j + 0];
        const unsigned long long p1 = coarse[(size_t)st + j + 1];
        const unsigned long long p2 = coarse[(size_t)st + j + 2];
        const unsigned long long p3 = coarse[(size_t)st + j + 3];
        const float4 v0 = *(const float4*)(hw + (size_t)(((unsigned)p0) >> SHIFT) * OUT_F + q * 4);
        const float4 v1 = *(const float4*)(hw + (size_t)(((unsigned)p1) >> SHIFT) * OUT_F + q * 4);
        const float4 v2 = *(const float4*)(hw + (size_t)(((unsigned)p2) >> SHIFT) * OUT_F + q * 4);
        const float4 v3 = *(const float4*)(hw + (size_t)(((unsigned)p3) >> SHIFT) * OUT_F + q * 4);
        const float o0 = __uint_as_float((unsigned)(p0 >> 32));
        const float o1 = __uint_as_float((unsigned)(p1 >> 32));
        const float o2 = __uint_as_float((unsigned)(p2 >> 32));
        const float o3 = __uint_as_float((unsigned)(p3 >> 32));
        acc.x = fmaf(o0, v0.x, acc.x); acc.y = fmaf(o0, v0.y, acc.y);
        acc.z = fmaf(o0, v0.z, acc.z); acc.w = fmaf(o0, v0.w, acc.w);
        acc.x = fmaf(o1, v1.x, acc.x); acc.y = fmaf(o1, v1.y, acc.y);
        acc.z = fmaf(o1, v1.z, acc.z); acc.w = fmaf(o1, v1.w, acc.w);
        acc.x = fmaf(o2, v2.x, acc.x); acc.y = fmaf(o2, v2.y, acc.y);
        acc.z = fmaf(o2, v2.z, acc.z); acc.w = fmaf(o2, v2.w, acc.w);
        acc.x = fmaf(o3, v3.x, acc.x); acc.y = fmaf(o3, v3.y, acc.y);
        acc.z = fmaf(o3, v3.z, acc.z); acc.w = fmaf(o3, v3.w, acc.w);
    }
    for (; j < dg; ++j) {
        const unsigned long long p = coarse[(size_t)st + j];
        const float o = __uint_as_float((unsigned)(p >> 32));
        const float4 v = *(const float4*)(hw + (size_t)(((unsigned)p) >> SHIFT) * OUT_F + q * 4);
        acc.x = fmaf(o, v.x, acc.x);
        acc.y = fmaf(o, v.y, acc.y);
        acc.z = fmaf(o, v.z, acc.z);
        acc.w = fmaf(o, v.w, acc.w);
    }

    const float norm = 1.0f / fmaxf((float)dg, 1.0f);
    const float4 bb  = *(const float4*)(bias + q * 4);
    float4 r;
    r.x = fmaxf(fmaf(acc.x, norm, bb.x), 0.f);
    r.y = fmaxf(fmaf(acc.y, norm, bb.y), 0.f);
    r.z = fmaxf(fmaf(acc.z, norm, bb.z), 0.f);
    r.w = fmaxf(fmaf(acc.w, norm, bb.w), 0.f);
    *(float4*)(out + (size_t)n * OUT_F + q * 4) = r;
}

extern "C" void kernel_launch(void* const* d_in, const int* in_sizes, int n_in,
                              void* d_out, int out_size, void* d_ws, size_t ws_size,
                              hipStream_t stream) {
    const float* h   = (const float*)d_in[0];
    const int*   src = (const int*)  d_in[1];
    const int*   dst = (const int*)  d_in[2];
    const float* ord = (const float*)d_in[3];
    const float* W   = (const float*)d_in[4];
    const float* b   = (const float*)d_in[5];
    float*       out = (float*)d_out;

    // ws layout (~26.5 MB): coarse u64[E] | hw f32[N*32] |
    //   binTot[NB] | binStart[NB] | cursor[NB] | nodeStart[NB*64] | nodeCnt[NB*64]
    unsigned long long* coarse = (unsigned long long*)d_ws;
    float* hw        = (float*)(coarse + N_EDGES);
    int*   binTot    = (int*)(hw + (size_t)N_NODES * OUT_F);
    int*   binStart  = binTot + NB;
    int*   cursor    = binStart + NB;
    int*   nodeStart = cursor + NB;
    int*   nodeCnt   = nodeStart + NB * NPB;

    hipLaunchKernelGGL(gemm64x32_zero, dim3(N_NODES / 8), dim3(256), 0, stream,
                       h, W, hw, binTot);
    hipLaunchKernelGGL(k_count, dim3(CBLOCKS), dim3(256), 0, stream, dst, binTot);
    hipLaunchKernelGGL(k_scan, dim3(1), dim3(256), 0, stream,
                       binTot, binStart, cursor);
    hipLaunchKernelGGL(k_part, dim3(PBLOCKS), dim3(PTH), 0, stream,
                       src, dst, ord, cursor, coarse);
    hipLaunchKernelGGL(k_sort, dim3(NB), dim3(512), 0, stream,
                       coarse, binStart, binTot, nodeStart, nodeCnt);
    hipLaunchKernelGGL(k_gather2, dim3(N_NODES * 8 / 256), dim3(256), 0, stream,
                       coarse, nodeStart, nodeCnt, hw, b, out);
}